// Round 6
// baseline (122.861 us; speedup 1.0000x reference)
//
#include <hip/hip_runtime.h>
#include <stdint.h>

#define TOKENS  256
#define INF     4096
#define OUTF    11008
#define NGROUPS 32
#define KSPLIT  2
#define PHK     128                       // K per phase = one quant group
#define NPH     ((INF / KSPLIT) / PHK)    // 16 phases per block
#define NTH     256

typedef __attribute__((ext_vector_type(2))) _Float16 f16x2;
typedef __attribute__((ext_vector_type(8))) _Float16 f16x8;
typedef __attribute__((ext_vector_type(2))) __fp16   pkh2;
typedef __attribute__((ext_vector_type(4))) float    f32x4;

union U32H2 { uint32_t u; f16x2 h; };
union H8    { f16x2 h2[4]; f16x8 h8; };
union PK    { pkh2 p; f16x2 h; };

// ---------------- pre-kernel: x fp32 -> FRAGMENT-LINEAR fp16 + {out<-bias} ---
// x16f slot s = (mtile*512 + kblk8)*16 + l16  (16B per slot, 131072 slots):
//   slot holds x[mtile*16 + l16][kblk8*8 .. +8] as f16, (i, i+4) pair-permuted
//   (exactly the 8 f16 one lane feeds the 16x16x32 f16 MFMA A-fragment).
// A main-kernel af load (fixed mi,s,P) then reads 4 x 256B contiguous segments
// (quad-major, l16-minor) -> 16 cache lines/instr, L2-resident. This fixes
// R4's failure (row-scattered af: 64 lines/instr, TA-bound) while keeping its
// barrier-free structure.
__global__ __launch_bounds__(NTH)
void prep(const float* __restrict__ x, _Float16* __restrict__ x16f,
          const float* __restrict__ bias, float* __restrict__ out) {
    const int b = blockIdx.x;
    if (b < 512) {
        const int t     = b * NTH + threadIdx.x;  // slot id 0..131071
        const int mtile = t >> 13;                // 0..15
        const int rem   = t & 8191;
        const int kb8   = rem >> 4;               // 0..511
        const int l16   = rem & 15;
        const int row   = mtile * 16 + l16;
        const float* p = x + (size_t)row * INF + kb8 * 8;
        f32x4 v0 = *(const f32x4*)p;
        f32x4 v1 = *(const f32x4*)(p + 4);
        H8 o; PK k0, k1, k2, k3;
        k0.p = __builtin_amdgcn_cvt_pkrtz(v0[0], v1[0]);
        k1.p = __builtin_amdgcn_cvt_pkrtz(v0[1], v1[1]);
        k2.p = __builtin_amdgcn_cvt_pkrtz(v0[2], v1[2]);
        k3.p = __builtin_amdgcn_cvt_pkrtz(v0[3], v1[3]);
        o.h2[0] = k0.h; o.h2[1] = k1.h; o.h2[2] = k2.h; o.h2[3] = k3.h;
        *(f16x8*)(x16f + (size_t)t * 8) = o.h8;
    } else {
        const int t = (b - 512) * NTH + threadIdx.x;  // 0 .. 704511
        const int c = t % (OUTF / 4);
        const int r = t / (OUTF / 4);
        const f32x4 bv = ((const f32x4*)bias)[c];
        ((f32x4*)out)[(size_t)r * (OUTF / 4) + c] = bv;
    }
}

// ---------------- main kernel: 64x128 tile, NO LDS / NO BARRIER / NO ASM -----
// R6: barrier-free retry of R4 with fragment-linear A. Five rounds showed the
// phase wall (~7000cy vs ~1600cy of pipe work) is the barrier convoy + LDS
// round-trip, not occupancy (R1), not barrier-drain counting (R2), not B
// latency (R5). Here waves are fully independent dataflow: af comes straight
// from L2 (coalesced by layout), B double-buffered in registers, compiler
// free to software-pipeline across phases. KSPLIT=2 (R3: 4 blows atomics).
__global__ __launch_bounds__(NTH, 4)
void qlin_main(const _Float16* __restrict__ x16f,
               const uint32_t* __restrict__ qweight,
               const uint32_t* __restrict__ qzeros,
               const float* __restrict__ scales,
               float* __restrict__ out)
{
    const int tid = threadIdx.x;

    // ---- XCD-chunked block decode: 86 strips x 8 members over 8 XCDs ----
    // (proven R1/R2/R5: FETCH_SIZE == 22.5MB == qweight read exactly once)
    const int d  = blockIdx.x;            // HW XCD = d & 7 (round-robin)
    const int cx = d & 7, kk = d >> 3;    // kk in 0..85
    int strip, memb;
    if (kk < 80) { strip = cx * 10 + (kk >> 3); memb = kk & 7; }
    else         { const int t2 = ((kk - 80) << 3) | cx; strip = 80 + (t2 >> 3); memb = t2 & 7; }
    const int bx = strip;                 // 0..85  out-feature block
    const int by = memb >> 1;             // 0..3   token block
    const int ks = memb & 1;              // 0..1   K half

    const int lane = tid & 63;
    const int quad = lane >> 4;
    const int l16  = lane & 15;
    const int wv   = tid >> 6;            // 0..3, wave's 32-col strip

    // ---- A map: fragment-linear, per-lane base + compile-time strides ----
    // byte(mi,P,s) = by*524288 + ks*65536 + mi*131072 + P*4096 + s*1024
    //              + quad*256 + l16*16
    const char* aLane = (const char*)x16f
        + (size_t)by * 524288 + ks * 65536 + quad * 256 + l16 * 16;

    // ---- B map ----
    const int col0 = bx * 128 + wv * 32 + l16;   // nf=0 column
    const int col1 = col0 + 16;                  // nf=1 column
    const int bOff0 = quad * OUTF + col0;
    const int bOff1 = quad * OUTF + col1;
    const int zsh   = (col0 & 7) * 4;            // same for col1
    const int qrow0 = ks * (INF / KSPLIT / 8);   // 0 or 256
    const int g0    = ks * (NGROUPS / KSPLIT);   // 0 or 16

    f32x4 acc[4][2];
#pragma unroll
    for (int mi = 0; mi < 4; ++mi)
#pragma unroll
        for (int nf = 0; nf < 2; ++nf)
            acc[mi][nf] = f32x4{0.f, 0.f, 0.f, 0.f};

    uint32_t Breg[2][8];
    float    sS[2][2];
    uint32_t qZ[2][2];

    // ================= prologue: phase 0 B-side prefetch =================
    {
        sS[0][0] = scales[g0 * OUTF + col0];
        sS[0][1] = scales[g0 * OUTF + col1];
        qZ[0][0] = qzeros[g0 * (OUTF / 8) + (col0 >> 3)];
        qZ[0][1] = qzeros[g0 * (OUTF / 8) + (col1 >> 3)];
        const uint32_t* qp = qweight + (size_t)qrow0 * OUTF;
#pragma unroll
        for (int s = 0; s < 4; ++s) {
            Breg[0][2 * s + 0] = qp[(size_t)(s * 4) * OUTF + bOff0];
            Breg[0][2 * s + 1] = qp[(size_t)(s * 4) * OUTF + bOff1];
        }
    }

    // ================= phase loop (ROLLED, 2 phases per iteration) ============
#define PHASE_BODY(PAR, P, DO_PREFETCH)                                          \
    {                                                                            \
        if (DO_PREFETCH) {                                                       \
            const int pn = (P) + 1;                                              \
            const int gn = g0 + pn;                                              \
            sS[1 - (PAR)][0] = scales[gn * OUTF + col0];                         \
            sS[1 - (PAR)][1] = scales[gn * OUTF + col1];                         \
            qZ[1 - (PAR)][0] = qzeros[gn * (OUTF / 8) + (col0 >> 3)];            \
            qZ[1 - (PAR)][1] = qzeros[gn * (OUTF / 8) + (col1 >> 3)];            \
            const uint32_t* qpb = qweight + (size_t)(qrow0 + pn * 16) * OUTF;    \
            _Pragma("unroll")                                                    \
            for (int s = 0; s < 4; ++s) {                                        \
                Breg[1 - (PAR)][2 * s + 0] = qpb[(size_t)(s * 4) * OUTF + bOff0];\
                Breg[1 - (PAR)][2 * s + 1] = qpb[(size_t)(s * 4) * OUTF + bOff1];\
            }                                                                    \
        }                                                                        \
        f16x2 hs2[2], hz2[2];                                                    \
        _Pragma("unroll")                                                        \
        for (int nf = 0; nf < 2; ++nf) {                                         \
            const float s = sS[PAR][nf];                                         \
            const int   z = (int)((qZ[PAR][nf] >> zsh) & 15u) + 1025;            \
            const _Float16 hs = (_Float16)s;                                     \
            const _Float16 hz = (_Float16)(-(float)z);                           \
            hs2[nf] = f16x2{hs, hs};                                             \
            hz2[nf] = f16x2{hz, hz};                                             \
        }                                                                        \
        const char* aP = aLane + (P) * 4096;                                     \
        _Pragma("unroll")                                                        \
        for (int s = 0; s < 4; ++s) {                                            \
            f16x8 af[4];                                                         \
            _Pragma("unroll")                                                    \
            for (int mi = 0; mi < 4; ++mi)                                       \
                af[mi] = *(const f16x8*)(aP + mi * 131072 + s * 1024);           \
            _Pragma("unroll")                                                    \
            for (int nf = 0; nf < 2; ++nf) {                                     \
                const uint32_t q = Breg[PAR][2 * s + nf];                        \
                H8 b;                                                            \
                _Pragma("unroll")                                                \
                for (int j = 0; j < 4; ++j) {                                    \
                    U32H2 u;                                                     \
                    u.u = ((q >> (4 * j)) & 0x000F000Fu) | 0x64006400u;          \
                    b.h2[j] = (u.h + hz2[nf]) * hs2[nf];                         \
                }                                                                \
                __builtin_amdgcn_s_setprio(1);                                   \
                _Pragma("unroll")                                                \
                for (int mi = 0; mi < 4; ++mi)                                   \
                    acc[mi][nf] = __builtin_amdgcn_mfma_f32_16x16x32_f16(        \
                        af[mi], b.h8, acc[mi][nf], 0, 0, 0);                     \
                __builtin_amdgcn_s_setprio(0);                                   \
            }                                                                    \
        }                                                                        \
    }

#pragma unroll 1
    for (int pp = 0; pp < NPH / 2; ++pp) {
        PHASE_BODY(0, 2 * pp, true)
        PHASE_BODY(1, 2 * pp + 1, (pp < NPH / 2 - 1))
    }
#undef PHASE_BODY

    // ================= epilogue: atomic partial accumulate =================
#pragma unroll
    for (int nf = 0; nf < 2; ++nf) {
        const int col = (nf == 0) ? col0 : col1;
#pragma unroll
        for (int mi = 0; mi < 4; ++mi) {
            const int r0 = by * 64 + mi * 16 + quad * 4;
#pragma unroll
            for (int rg = 0; rg < 4; ++rg)
                unsafeAtomicAdd(&out[(size_t)(r0 + rg) * OUTF + col],
                                acc[mi][nf][rg]);
        }
    }
}

// ---------------- fallback (proven R2 kernel) if ws too small ----------------
__global__ __launch_bounds__(NTH, 2)
void qlin_fb(const float* __restrict__ x,
             const uint32_t* __restrict__ qweight,
             const uint32_t* __restrict__ qzeros,
             const float* __restrict__ scales,
             const float* __restrict__ bias,
             float* __restrict__ out)
{
    __shared__ alignas(16) _Float16 Asb[64][40];
    __shared__ alignas(16) _Float16 Bsb[128][40];
    const int tid = threadIdx.x;
    const int bx = blockIdx.x, by = blockIdx.y;
    const int am = tid >> 2, ar = tid & 3;
    const float* xrow = x + (size_t)(by * 64 + am) * INF + ar * 8;
    const int bc = tid & 127, br = tid >> 7;
    const int bn = bx * 128 + bc;
    const int bswz = (bc >> 3) & 3;
    const int lane = tid & 63, quad = lane >> 4, l16 = lane & 15;
    const int wv = tid >> 6, wm = wv >> 1, wn = wv & 1;
    f32x4 acc[2][4];
#pragma unroll
    for (int i = 0; i < 2; ++i)
#pragma unroll
        for (int j = 0; j < 4; ++j) acc[i][j] = f32x4{0.f, 0.f, 0.f, 0.f};
    f32x4 pa0 = *(const f32x4*)(xrow + 0);
    f32x4 pa1 = *(const f32x4*)(xrow + 4);
    uint32_t pq0 = qweight[(size_t)br * OUTF + bn];
    uint32_t pq1 = qweight[(size_t)(br + 2) * OUTF + bn];
    for (int g = 0; g < NGROUPS; ++g) {
        const float s = scales[g * OUTF + bn];
        const uint32_t qzv = qzeros[g * (OUTF / 8) + (bn >> 3)];
        const int z = (int)((qzv >> (4 * (bn & 7))) & 15u) + 1;
        const _Float16 hs = (_Float16)s;
        const _Float16 hz = (_Float16)(-(float)(1024 + z));
        const f16x2 hs2 = {hs, hs}, hz2 = {hz, hz};
#pragma unroll
        for (int t4 = 0; t4 < 4; ++t4) {
            const int it = (g << 2) + t4;
            { H8 ah; PK p0, p1, p2, p3;
              p0.p = __builtin_amdgcn_cvt_pkrtz(pa0[0], pa1[0]);
              p1.p = __builtin_amdgcn_cvt_pkrtz(pa0[1], pa1[1]);
              p2.p = __builtin_amdgcn_cvt_pkrtz(pa0[2], pa1[2]);
              p3.p = __builtin_amdgcn_cvt_pkrtz(pa0[3], pa1[3]);
              ah.h2[0] = p0.h; ah.h2[1] = p1.h; ah.h2[2] = p2.h; ah.h2[3] = p3.h;
              *(f16x8*)&Asb[am][ar * 8] = ah.h8; }
            { const uint32_t qq[2] = {pq0, pq1};
#pragma unroll
              for (int rr = 0; rr < 2; ++rr) {
                  const int r = br + rr * 2; H8 bh;
#pragma unroll
                  for (int jp = 0; jp < 4; ++jp) {
                      U32H2 u; u.u = ((qq[rr] >> (4 * jp)) & 0x000F000Fu) | 0x64006400u;
                      bh.h2[jp] = (u.h + hz2) * hs2;
                  }
                  *(f16x8*)&Bsb[bc][(r ^ bswz) * 8] = bh.h8;
              } }
            __syncthreads();
            const int itn = (it < 127) ? it + 1 : 127;
            pa0 = *(const f32x4*)(xrow + itn * 32);
            pa1 = *(const f32x4*)(xrow + itn * 32 + 4);
            pq0 = qweight[(size_t)(itn * 4 + br) * OUTF + bn];
            pq1 = qweight[(size_t)(itn * 4 + br + 2) * OUTF + bn];
            f16x8 af[2], bf[4];
#pragma unroll
            for (int mi = 0; mi < 2; ++mi)
                af[mi] = *(const f16x8*)&Asb[wm * 32 + mi * 16 + l16][quad * 8];
#pragma unroll
            for (int ni = 0; ni < 4; ++ni) {
                const int c = wn * 64 + ni * 16 + l16;
                bf[ni] = *(const f16x8*)&Bsb[c][(quad ^ ((c >> 3) & 3)) * 8];
            }
#pragma unroll
            for (int mi = 0; mi < 2; ++mi)
#pragma unroll
                for (int ni = 0; ni < 4; ++ni)
                    acc[mi][ni] = __builtin_amdgcn_mfma_f32_16x16x32_f16(
                        af[mi], bf[ni], acc[mi][ni], 0, 0, 0);
            __syncthreads();
        }
    }
#pragma unroll
    for (int ni = 0; ni < 4; ++ni) {
        const int col = bx * 128 + wn * 64 + ni * 16 + l16;
        const float bv = bias[col];
#pragma unroll
        for (int mi = 0; mi < 2; ++mi) {
            const int row0 = by * 64 + wm * 32 + mi * 16 + quad * 4;
#pragma unroll
            for (int rg = 0; rg < 4; ++rg)
                out[(size_t)(row0 + rg) * OUTF + col] = acc[mi][ni][rg] + bv;
        }
    }
}

extern "C" void kernel_launch(void* const* d_in, const int* in_sizes, int n_in,
                              void* d_out, int out_size, void* d_ws, size_t ws_size,
                              hipStream_t stream) {
    const float*    xx = (const float*)d_in[0];
    const uint32_t* qw = (const uint32_t*)d_in[1];
    const uint32_t* qz = (const uint32_t*)d_in[2];
    const float*    sc = (const float*)d_in[3];
    const float*    bs = (const float*)d_in[4];
    float* out = (float*)d_out;

    const size_t x16_bytes = (size_t)TOKENS * INF * sizeof(_Float16);  // 2 MB
    if (ws_size >= x16_bytes) {
        _Float16* x16f = (_Float16*)d_ws;
        prep<<<512 + (TOKENS * OUTF / 4) / NTH, NTH, 0, stream>>>(xx, x16f, bs, out);
        qlin_main<<<(OUTF / 128) * (TOKENS / 64) * KSPLIT, NTH, 0, stream>>>(
            x16f, qw, qz, sc, out);
    } else {
        dim3 grid(OUTF / 128, TOKENS / 64);
        qlin_fb<<<grid, NTH, 0, stream>>>(xx, qw, qz, sc, bs, out);
    }
}